// Round 9
// baseline (164.408 us; speedup 1.0000x reference)
//
#include <hip/hip_runtime.h>

#define B_ 4
#define N_ 4096
#define C_ 256
#define M_ 2048

typedef __attribute__((ext_vector_type(8))) short short8;
typedef __attribute__((ext_vector_type(4))) short short4v;
typedef __attribute__((ext_vector_type(4))) float f32x4;

union U16x8 { uint4 u4; unsigned short us[8]; short8 s8; };
union U16x4 { uint2 u2; unsigned short us[4]; short4v s4; };

__device__ __forceinline__ float bf2f(unsigned short h) {
    unsigned int u = ((unsigned int)h) << 16;
    return __builtin_bit_cast(float, u);
}
__device__ __forceinline__ unsigned short f2bf(float f) {
    unsigned int u = __builtin_bit_cast(unsigned int, f);
    u += 0x7FFFu + ((u >> 16) & 1u);
    return (unsigned short)(u >> 16);
}

#define GLB_AS(p) ((const __attribute__((address_space(1))) unsigned int*)(p))
#define LDS_AS(p) ((__attribute__((address_space(3))) unsigned int*)(p))

// 16x16x16 bf16 MFMA: builtin if available, else raw encoding via inline asm.
__device__ __forceinline__ f32x4 mfma16x16(short4v a, short4v b, f32x4 c) {
#if __has_builtin(__builtin_amdgcn_mfma_f32_16x16x16bf16_1k)
    return __builtin_amdgcn_mfma_f32_16x16x16bf16_1k(a, b, c, 0, 0, 0);
#else
    asm("v_mfma_f32_16x16x16_bf16 %0, %1, %2, %0" : "+v"(c) : "v"(a), "v"(b));
    return c;
#endif
}

// ---- Fused prepass (WIDE): norms + casts. grid (M/64, B), 1024 thr ----
__global__ __launch_bounds__(1024) void k_prep(const float* __restrict__ g,
                                               unsigned short* __restrict__ gcm,
                                               unsigned short* __restrict__ gmc) {
    __shared__ float red[16][64];
    __shared__ float sInv[64];
    __shared__ unsigned short T[64 * 66];   // normalized [c][m] tile, odd-dword stride
    const int b = blockIdx.y, m0 = blockIdx.x * 64;
    const int tid = threadIdx.x;                // 0..1023
    const int ml = tid & 63, cq = tid >> 6;     // cq in [0,16)

    // phase 1: norms — each thread sums 16 c-rows
    const float* gb = g + (size_t)b * C_ * M_ + m0 + ml;
    float ss = 0.f;
#pragma unroll 4
    for (int i = 0; i < 16; ++i) {
        float v = gb[(size_t)(cq * 16 + i) * M_];
        ss += v * v;
    }
    red[cq][ml] = ss;
    __syncthreads();
    if (cq == 0) {
        float t = 0.f;
#pragma unroll
        for (int k = 0; k < 16; ++k) t += red[k][ml];
        sInv[ml] = 1.f / fmaxf(sqrtf(t), 1e-8f);
    }
    __syncthreads();

    // phase 2: casts, 4 c-tiles of 64
    for (int c0 = 0; c0 < C_; c0 += 64) {
        const float* gbase = g + ((size_t)b * C_ + c0) * M_ + m0;
        unsigned short* gcmb = gcm + ((size_t)b * C_ + c0) * M_ + m0;
        {
            int id = tid;                       // 1024 float4-chunks, 1 per thread
            int ci = id >> 4, mq = (id & 15) * 4;
            float4 v = *(const float4*)(gbase + (size_t)ci * M_ + mq);
            uint2 pk;
            pk.x = (unsigned)f2bf(v.x) | ((unsigned)f2bf(v.y) << 16);
            pk.y = (unsigned)f2bf(v.z) | ((unsigned)f2bf(v.w) << 16);
            *(uint2*)(gcmb + (size_t)ci * M_ + mq) = pk;
            T[ci * 66 + mq + 0] = f2bf(v.x * sInv[mq + 0]);
            T[ci * 66 + mq + 1] = f2bf(v.y * sInv[mq + 1]);
            T[ci * 66 + mq + 2] = f2bf(v.z * sInv[mq + 2]);
            T[ci * 66 + mq + 3] = f2bf(v.w * sInv[mq + 3]);
        }
        __syncthreads();
        unsigned short* gmcb = gmc + ((size_t)b * M_ + m0) * C_ + c0;
        if (tid < 512) {                        // 512 8-short chunks
            int mr = tid >> 3, cc8 = (tid & 7) * 8;
            U16x8 t;
#pragma unroll
            for (int k = 0; k < 8; ++k) t.us[k] = T[(cc8 + k) * 66 + mr];
            *(uint4*)(gmcb + (size_t)mr * C_ + cc8) = t.u4;
        }
        __syncthreads();   // T reused next tile
    }
}

// ---------------- Main fused kernel (v15) ----------------
// v14's verified dbuf plumbing + S/O SOFTWARE PIPELINE: body t computes
// GEMM1(t+1)+softmax(t+1) (producing pk for the NEXT body) while GEMM2(t)
// consumes the pk produced by the PREVIOUS body. pk is ping-ponged (pkE/pkO,
// all-static, rule #20), so softmax-VALU and GEMM2-MFMA in one body are
// data-independent -> scheduler + natural wave drift overlap them (v10/v14's
// serial GEMM1->SM->GEMM2 chain left MFMA and VALU pipes alternately idle:
// MfmaUtil 29 + VALUBusy 32 at 2 waves/SIMD).
// DMA schedule: body t stages A(t+3)->Abuf[(t+1)&1] and B(t+2)->Bbuf[t&1]
// AFTER its barrier (buffers just-read this body); every tile lands one full
// body before use. Tile 2 staged after an extra prologue barrier.
__global__ __launch_bounds__(512, 1) void k_main(
    const float* __restrict__ l,
    const unsigned short* __restrict__ gcm,    // [B][C][M] raw bf16   (GEMM2 B, k=m contig)
    const unsigned short* __restrict__ gmc,    // [B][M][C] normalized (GEMM1 A, k=c contig)
    float* __restrict__ out)
{
    __shared__ __align__(16) char sMem[132096];
    unsigned short* sGmcD = (unsigned short*)sMem;             // ghat [2][64][256], 2x32 KB
    unsigned short* sGcmD = (unsigned short*)(sMem + 65536);   // graw [2][256][64], 2x32 KB
    float (*sDen)[64] = (float (*)[64])(sMem + 131072);        // [4 kh][64 rows]

    const int tid = threadIdx.x;
    const int w = tid >> 6;
    const int lane = tid & 63;
    const int l15 = lane & 15;
    const int quad = lane >> 4;
    const int kh = w & 3;        // key-quarter
    const int rh = w >> 2;       // row-half

    // ---- batch-clustered XCD swizzle (bijective over 256 blocks) ----
    const int bid = blockIdx.x;
    const int xcd = bid & 7;
    const int b = xcd >> 1;                                   // 2 XCDs per batch
    const int row0 = (((bid >> 3) << 1) | (xcd & 1)) * 64;    // 64-row tile in [0,4096)

    // per-lane DMA source offsets (shorts), XOR chunk swizzles match the read patterns
    int goffA[4], goffB[4];
#pragma unroll
    for (int i = 0; i < 4; ++i) {
        int p = (w * 4 + i) * 64 + lane;                   // p in [0,2048)
        int rA = p >> 5;                                   // row in [0,64), 32 granules/row
        goffA[i] = rA * 256 + (((p & 31) ^ (rA & 31)) << 3);
        int rB = p >> 3;                                   // row in [0,256), 8 granules/row
        goffB[i] = rB * 2048 + (((p & 7) ^ ((rB >> 1) & 7)) << 3);
    }

    const unsigned short* gmc_b = gmc + (size_t)b * M_ * C_;
    const unsigned short* gcm_b = gcm + (size_t)b * C_ * M_;

    // tile = 64-key tile index in [0,32). Unit-safe: scale INTERNALLY (v14-verified).
    auto dmaA = [&](int tile, int buf) {
#pragma unroll
        for (int i = 0; i < 4; ++i)
            __builtin_amdgcn_global_load_lds(GLB_AS(gmc_b + (size_t)tile * 16384 + goffA[i]),
                                             LDS_AS(&sGmcD[buf * 16384 + (w * 4 + i) * 512]), 16, 0, 0);
    };
    auto dmaB = [&](int tile, int buf) {
#pragma unroll
        for (int i = 0; i < 4; ++i)
            __builtin_amdgcn_global_load_lds(GLB_AS(gcm_b + (size_t)tile * 64 + goffB[i]),
                                             LDS_AS(&sGcmD[buf * 16384 + (w * 4 + i) * 512]), 16, 0, 0);
    };

    // stage tiles 0 and 1; drained at pre-loop barrier
    dmaA(0, 0);
    dmaB(0, 0);
    dmaA(1, 1);
    dmaB(1, 1);

    // ---- Q: my 32 rows (row-half rh), row norm, normalize -> bf16 B-frags ----
    short8 qf[2][8];
#pragma unroll
    for (int rt = 0; rt < 2; ++rt) {
        const float* lrow = l + ((size_t)b * N_ + row0 + rh * 32 + rt * 16 + l15) * C_;
        U16x8 qt[8];
        float ss = 0.f;
#pragma unroll
        for (int kk = 0; kk < 8; ++kk) {
            float4 x0 = *(const float4*)(lrow + kk * 32 + quad * 8);
            float4 x1 = *(const float4*)(lrow + kk * 32 + quad * 8 + 4);
            ss += x0.x*x0.x + x0.y*x0.y + x0.z*x0.z + x0.w*x0.w;
            ss += x1.x*x1.x + x1.y*x1.y + x1.z*x1.z + x1.w*x1.w;
            qt[kk].us[0] = f2bf(x0.x); qt[kk].us[1] = f2bf(x0.y);
            qt[kk].us[2] = f2bf(x0.z); qt[kk].us[3] = f2bf(x0.w);
            qt[kk].us[4] = f2bf(x1.x); qt[kk].us[5] = f2bf(x1.y);
            qt[kk].us[6] = f2bf(x1.z); qt[kk].us[7] = f2bf(x1.w);
        }
        ss += __shfl_xor(ss, 16);
        ss += __shfl_xor(ss, 32);
        const float invl = 1.0f / fmaxf(sqrtf(ss), 1e-8f);
#pragma unroll
        for (int kk = 0; kk < 8; ++kk) {
            U16x8 t;
#pragma unroll
            for (int j = 0; j < 8; ++j) t.us[j] = f2bf(bf2f(qt[kk].us[j]) * invl);
            qf[rt][kk] = t.s8;
        }
    }

    __syncthreads();   // barrier #1: DMA tiles 0+1 drained; tile 0 ready

    f32x4 zero = {0.f, 0.f, 0.f, 0.f};
    f32x4 o[2][16];    // per-wave PARTIAL O (its 16 keys): [row-tile][c-tile 16c]
#pragma unroll
    for (int i = 0; i < 2; ++i)
#pragma unroll
        for (int j = 0; j < 16; ++j) o[i][j] = zero;
    float dl0 = 0.f, dl1 = 0.f;

    const unsigned short* gAbase = &sGmcD[(kh * 16 + l15) * 256];
    const int rxor = (kh * 16 + l15) & 31;
    const int chunkXor = (kh * 4 + quad) ^ (l15 & 14);
    const unsigned short* gBbase = &sGcmD[l15 * 64 + (chunkXor << 2)];

    f32x4 sa0, sa1;
    U16x4 pkE0, pkE1, pkO0, pkO1;   // pk ping-pong by tile parity (all-static)

#define G1(PAR) do {                                                           \
        sa0 = zero; sa1 = zero;                                                \
        const unsigned short* gA_ = gAbase + (PAR) * 16384;                    \
        _Pragma("unroll")                                                      \
        for (int kk = 0; kk < 8; ++kk) {                                       \
            short8 ag = *(const short8*)&gA_[((kk * 4 + quad) ^ rxor) << 3];   \
            sa0 = __builtin_amdgcn_mfma_f32_16x16x32_bf16(ag, qf[0][kk], sa0, 0, 0, 0); \
            sa1 = __builtin_amdgcn_mfma_f32_16x16x32_bf16(ag, qf[1][kk], sa1, 0, 0, 0); \
        }                                                                      \
    } while (0)

#define SM(PK0, PK1) do {                                                      \
        _Pragma("unroll")                                                      \
        for (int r = 0; r < 4; ++r) {                                          \
            float p0 = exp2f(sa0[r] * 3.6067376022224085f);                    \
            float p1 = exp2f(sa1[r] * 3.6067376022224085f);                    \
            dl0 += p0; dl1 += p1;                                              \
            PK0.us[r] = f2bf(p0);                                              \
            PK1.us[r] = f2bf(p1);                                              \
        }                                                                      \
    } while (0)

#define G2(PAR, PK0, PK1) do {                                                 \
        const unsigned short* gB_ = gBbase + (PAR) * 16384;                    \
        _Pragma("unroll")                                                      \
        for (int ct = 0; ct < 16; ++ct) {                                      \
            short4v bb = *(const short4v*)&gB_[ct * 1024];                     \
            o[0][ct] = mfma16x16(PK0.s4, bb, o[0][ct]);                        \
            o[1][ct] = mfma16x16(PK1.s4, bb, o[1][ct]);                        \
        }                                                                      \
    } while (0)

    // ---- pipeline prologue: S-stage of tile 0 ----
    G1(0);                 // tile 0 from Abuf0
    SM(pkE0, pkE1);        // pk for tile 0
    __syncthreads();       // barrier #2: all waves' tile-0 A-reads done
    dmaA(2, 0);            // refill Abuf0 with tile 2 (drains at body-0 barrier)

    // ---- main loop: bodies t=0..27 (guard-free), tails peeled ----
    for (int t = 0; t < 28; t += 2) {
        // body even t: G1(t+1 odd, Abuf1) ; G2(t even, Bbuf0, pkE) ; SM -> pkO
        G1(1); SM(pkO0, pkO1); G2(0, pkE0, pkE1);
        __syncthreads();
        dmaA(t + 3, 1); dmaB(t + 2, 0);
        // body odd t+1: G1(t+2 even, Abuf0) ; G2(t+1 odd, Bbuf1, pkO) ; SM -> pkE
        G1(0); SM(pkE0, pkE1); G2(1, pkO0, pkO1);
        __syncthreads();
        dmaA(t + 4, 0); dmaB(t + 3, 1);
    }
    // t=28 (even): full
    G1(1); SM(pkO0, pkO1); G2(0, pkE0, pkE1);
    __syncthreads();
    dmaA(31, 1); dmaB(30, 0);
    // t=29 (odd): no A-stage (tile 32 doesn't exist)
    G1(0); SM(pkE0, pkE1); G2(1, pkO0, pkO1);
    __syncthreads();
    dmaB(31, 1);
    // t=30 (even): last S-stage (tile 31), no stages
    G1(1); SM(pkO0, pkO1); G2(0, pkE0, pkE1);
    __syncthreads();
    // t=31 (odd): O-stage only
    G2(1, pkO0, pkO1);

#undef G1
#undef SM
#undef G2

    // ---- denominators: quad-reduce, publish per key-quarter per row ----
    {
        float d0 = dl0;
        d0 += __shfl_xor(d0, 16);
        d0 += __shfl_xor(d0, 32);
        float d1 = dl1;
        d1 += __shfl_xor(d1, 16);
        d1 += __shfl_xor(d1, 32);
        if (quad == 0) {
            sDen[kh][rh * 32 + l15] = d0;
            sDen[kh][rh * 32 + 16 + l15] = d1;
        }
    }

    // ---- O reduction: 4 static rounds (rh x rt) through 64 KB LDS dump ----
    // slot(kh', j, quad, l15) = kh'*1024 + j*64 + quad*16 + l15  (f32x4 units)
    // All indices static (rule #20). red4 covers sMem[0,65536); sDen at 131072.
    f32x4* red4 = (f32x4*)sMem;
    const int wslot = kh * 1024 + quad * 16 + l15;       // + j*64
    const int rslot = (4 * kh) * 64 + quad * 16 + l15;   // + jj*64 + kh'*1024
    f32x4 oacc0[4], oacc1[4];

#define RED_ROUND(RH, OSRC, ODST)                                              \
    __syncthreads();                                                           \
    if (rh == (RH)) {                                                          \
        _Pragma("unroll")                                                      \
        for (int j = 0; j < 16; ++j) red4[wslot + j * 64] = OSRC[j];           \
    }                                                                          \
    __syncthreads();                                                           \
    if (rh == (RH)) {                                                          \
        _Pragma("unroll")                                                      \
        for (int jj = 0; jj < 4; ++jj) {                                       \
            const int base = rslot + jj * 64;                                  \
            ODST[jj] = red4[base] + red4[base + 1024] +                        \
                       red4[base + 2048] + red4[base + 3072];                  \
        }                                                                      \
    }

    RED_ROUND(0, o[0], oacc0)
    RED_ROUND(0, o[1], oacc1)
    RED_ROUND(1, o[0], oacc0)
    RED_ROUND(1, o[1], oacc1)
#undef RED_ROUND

    // ---- epilogue: wave (kh, rh) owns rows [32rh,32rh+32), c [64kh, 64kh+64) ----
    const float* lb = l + ((size_t)b * N_ + row0 + rh * 32) * C_;
    float* ob = out + ((size_t)b * N_ + row0 + rh * 32) * C_;
#pragma unroll
    for (int r = 0; r < 4; ++r) {
        {   // row-tile 0
            const int row = quad * 4 + r;
            const int grow = rh * 32 + row;
            const float inv = 1.f / (sDen[0][grow] + sDen[1][grow] + sDen[2][grow] + sDen[3][grow]);
            const size_t rb = (size_t)row * C_;
#pragma unroll
            for (int jj = 0; jj < 4; ++jj) {
                const int c = kh * 64 + jj * 16 + l15;
                ob[rb + c] = lb[rb + c] + oacc0[jj][r] * inv;
            }
        }
        {   // row-tile 1
            const int row = 16 + quad * 4 + r;
            const int grow = rh * 32 + row;
            const float inv = 1.f / (sDen[0][grow] + sDen[1][grow] + sDen[2][grow] + sDen[3][grow]);
            const size_t rb = (size_t)row * C_;
#pragma unroll
            for (int jj = 0; jj < 4; ++jj) {
                const int c = kh * 64 + jj * 16 + l15;
                ob[rb + c] = lb[rb + c] + oacc1[jj][r] * inv;
            }
        }
    }
}

extern "C" void kernel_launch(void* const* d_in, const int* in_sizes, int n_in,
                              void* d_out, int out_size, void* d_ws, size_t ws_size,
                              hipStream_t stream) {
    (void)in_sizes; (void)n_in; (void)out_size; (void)ws_size;
    const float* l = (const float*)d_in[0];
    const float* g = (const float*)d_in[1];
    float* outp = (float*)d_out;

    char* ws = (char*)d_ws;
    unsigned short* gmc = (unsigned short*)ws;                                   // 4 MB (normalized, [b][m][c])
    unsigned short* gcm = (unsigned short*)(ws + (size_t)B_ * M_ * C_ * 2);      // 4 MB (raw, [b][c][m])

    k_prep<<<dim3(M_ / 64, B_), 1024, 0, stream>>>(g, gcm, gmc);
    k_main<<<dim3(N_ / 64 * B_), 512, 0, stream>>>(l, gcm, gmc, outp);
}

// Round 10
// 147.345 us; speedup vs baseline: 1.1158x; 1.1158x over previous
//
#include <hip/hip_runtime.h>

#define B_ 4
#define N_ 4096
#define C_ 256
#define M_ 2048

typedef __attribute__((ext_vector_type(8))) short short8;
typedef __attribute__((ext_vector_type(4))) short short4v;
typedef __attribute__((ext_vector_type(4))) float f32x4;

union U16x8 { uint4 u4; unsigned short us[8]; short8 s8; };
union U16x4 { uint2 u2; unsigned short us[4]; short4v s4; };

__device__ __forceinline__ float bf2f(unsigned short h) {
    unsigned int u = ((unsigned int)h) << 16;
    return __builtin_bit_cast(float, u);
}
__device__ __forceinline__ unsigned short f2bf(float f) {
    unsigned int u = __builtin_bit_cast(unsigned int, f);
    u += 0x7FFFu + ((u >> 16) & 1u);
    return (unsigned short)(u >> 16);
}

#define GLB_AS(p) ((const __attribute__((address_space(1))) unsigned int*)(p))
#define LDS_AS(p) ((__attribute__((address_space(3))) unsigned int*)(p))

// 16x16x16 bf16 MFMA: builtin if available, else raw encoding via inline asm.
__device__ __forceinline__ f32x4 mfma16x16(short4v a, short4v b, f32x4 c) {
#if __has_builtin(__builtin_amdgcn_mfma_f32_16x16x16bf16_1k)
    return __builtin_amdgcn_mfma_f32_16x16x16bf16_1k(a, b, c, 0, 0, 0);
#else
    asm("v_mfma_f32_16x16x16_bf16 %0, %1, %2, %0" : "+v"(c) : "v"(a), "v"(b));
    return c;
#endif
}

// ---- Fused prepass (WIDE): norms + casts. grid (M/64, B), 1024 thr ----
__global__ __launch_bounds__(1024) void k_prep(const float* __restrict__ g,
                                               unsigned short* __restrict__ gcm,
                                               unsigned short* __restrict__ gmc) {
    __shared__ float red[16][64];
    __shared__ float sInv[64];
    __shared__ unsigned short T[64 * 66];   // normalized [c][m] tile, odd-dword stride
    const int b = blockIdx.y, m0 = blockIdx.x * 64;
    const int tid = threadIdx.x;                // 0..1023
    const int ml = tid & 63, cq = tid >> 6;     // cq in [0,16)

    // phase 1: norms — each thread sums 16 c-rows
    const float* gb = g + (size_t)b * C_ * M_ + m0 + ml;
    float ss = 0.f;
#pragma unroll 4
    for (int i = 0; i < 16; ++i) {
        float v = gb[(size_t)(cq * 16 + i) * M_];
        ss += v * v;
    }
    red[cq][ml] = ss;
    __syncthreads();
    if (cq == 0) {
        float t = 0.f;
#pragma unroll
        for (int k = 0; k < 16; ++k) t += red[k][ml];
        sInv[ml] = 1.f / fmaxf(sqrtf(t), 1e-8f);
    }
    __syncthreads();

    // phase 2: casts, 4 c-tiles of 64
    for (int c0 = 0; c0 < C_; c0 += 64) {
        const float* gbase = g + ((size_t)b * C_ + c0) * M_ + m0;
        unsigned short* gcmb = gcm + ((size_t)b * C_ + c0) * M_ + m0;
        {
            int id = tid;                       // 1024 float4-chunks, 1 per thread
            int ci = id >> 4, mq = (id & 15) * 4;
            float4 v = *(const float4*)(gbase + (size_t)ci * M_ + mq);
            uint2 pk;
            pk.x = (unsigned)f2bf(v.x) | ((unsigned)f2bf(v.y) << 16);
            pk.y = (unsigned)f2bf(v.z) | ((unsigned)f2bf(v.w) << 16);
            *(uint2*)(gcmb + (size_t)ci * M_ + mq) = pk;
            T[ci * 66 + mq + 0] = f2bf(v.x * sInv[mq + 0]);
            T[ci * 66 + mq + 1] = f2bf(v.y * sInv[mq + 1]);
            T[ci * 66 + mq + 2] = f2bf(v.z * sInv[mq + 2]);
            T[ci * 66 + mq + 3] = f2bf(v.w * sInv[mq + 3]);
        }
        __syncthreads();
        unsigned short* gmcb = gmc + ((size_t)b * M_ + m0) * C_ + c0;
        if (tid < 512) {                        // 512 8-short chunks
            int mr = tid >> 3, cc8 = (tid & 7) * 8;
            U16x8 t;
#pragma unroll
            for (int k = 0; k < 8; ++k) t.us[k] = T[(cc8 + k) * 66 + mr];
            *(uint4*)(gmcb + (size_t)mr * C_ + cc8) = t.u4;
        }
        __syncthreads();   // T reused next tile
    }
}

// ---------------- Main fused kernel (v16) ----------------
// v13 structure scaled to 16 WAVES (1024 thr), still 64 rows/block, 256 blocks.
// Rationale: v13's counters show no pipe above ~34% (MfmaUtil 29, VALUBusy 32,
// LDS ~34%) at 2 waves/SIMD -- latency/serialization-bound. 4 waves/SIMD
// doubles latency hiding. Pipelining attempts failed: v14 dbuf (-8%), v15
// S/O-pipeline (scratch spill: FETCH+WRITE +110MB). Per-wave state halves
// (kh in [0,4) keys, rh in [0,4) rows; 16 rows x 16 keys per wave; qf[8],
// o[16]) -> ~125 VGPR, fits the 128 cap of __launch_bounds__(1024,4).
// Cost accepted: A/V LDS reads 4x duplicated (was 2x).
__global__ __launch_bounds__(1024, 4) void k_main(
    const float* __restrict__ l,
    const unsigned short* __restrict__ gcm,    // [B][C][M] raw bf16   (GEMM2 B, k=m contig)
    const unsigned short* __restrict__ gmc,    // [B][M][C] normalized (GEMM1 A, k=c contig)
    float* __restrict__ out)
{
    __shared__ __align__(16) char sMem[66560];
    unsigned short* sGmc = (unsigned short*)sMem;              // ghat [m][c], 32 KB
    unsigned short* sGcm = (unsigned short*)(sMem + 32768);    // graw [c][m], 32 KB
    float (*sDen)[64] = (float (*)[64])(sMem + 65536);         // [4 kh][64 rows]

    const int tid = threadIdx.x;
    const int w = tid >> 6;      // 0..15
    const int lane = tid & 63;
    const int l15 = lane & 15;
    const int quad = lane >> 4;
    const int kh = w & 3;        // key-quarter
    const int rh = w >> 2;       // row-quarter (16 rows each)

    // ---- batch-clustered XCD swizzle (bijective over 256 blocks) ----
    const int bid = blockIdx.x;
    const int xcd = bid & 7;
    const int b = xcd >> 1;                                   // 2 XCDs per batch
    const int row0 = (((bid >> 3) << 1) | (xcd & 1)) * 64;    // 64-row tile in [0,4096)

    // per-lane DMA source offsets (shorts), XOR chunk swizzles match the read patterns
    int goffA[2], goffB[2];
#pragma unroll
    for (int i = 0; i < 2; ++i) {
        int p = (w * 2 + i) * 64 + lane;                   // p in [0,2048)
        int rA = p >> 5;                                   // row in [0,64), 32 granules/row
        goffA[i] = rA * 256 + (((p & 31) ^ (rA & 31)) << 3);
        int rB = p >> 3;                                   // row in [0,256), 8 granules/row
        goffB[i] = rB * 2048 + (((p & 7) ^ ((rB >> 1) & 7)) << 3);
    }

    const unsigned short* gmc_b = gmc + (size_t)b * M_ * C_;
    const unsigned short* gcm_b = gcm + (size_t)b * C_ * M_;

    // m0 = key index (v13 convention, proven): dmaA(mt*64)
    auto dmaA = [&](int m0) {
#pragma unroll
        for (int i = 0; i < 2; ++i)
            __builtin_amdgcn_global_load_lds(GLB_AS(gmc_b + (size_t)m0 * 256 + goffA[i]),
                                             LDS_AS(&sGmc[(w * 2 + i) * 512]), 16, 0, 0);
    };
    auto dmaB = [&](int m0) {
#pragma unroll
        for (int i = 0; i < 2; ++i)
            __builtin_amdgcn_global_load_lds(GLB_AS(gcm_b + (size_t)m0 + goffB[i]),
                                             LDS_AS(&sGcm[(w * 2 + i) * 512]), 16, 0, 0);
    };

    dmaA(0);
    dmaB(0);

    // ---- Q: my 16 rows (row-quarter rh), row norm, normalize -> bf16 B-frags ----
    short8 qf[8];
    {
        const float* lrow = l + ((size_t)b * N_ + row0 + rh * 16 + l15) * C_;
        U16x8 qt[8];
        float ss = 0.f;
#pragma unroll
        for (int kk = 0; kk < 8; ++kk) {
            float4 x0 = *(const float4*)(lrow + kk * 32 + quad * 8);
            float4 x1 = *(const float4*)(lrow + kk * 32 + quad * 8 + 4);
            ss += x0.x*x0.x + x0.y*x0.y + x0.z*x0.z + x0.w*x0.w;
            ss += x1.x*x1.x + x1.y*x1.y + x1.z*x1.z + x1.w*x1.w;
            qt[kk].us[0] = f2bf(x0.x); qt[kk].us[1] = f2bf(x0.y);
            qt[kk].us[2] = f2bf(x0.z); qt[kk].us[3] = f2bf(x0.w);
            qt[kk].us[4] = f2bf(x1.x); qt[kk].us[5] = f2bf(x1.y);
            qt[kk].us[6] = f2bf(x1.z); qt[kk].us[7] = f2bf(x1.w);
        }
        ss += __shfl_xor(ss, 16);
        ss += __shfl_xor(ss, 32);
        const float invl = 1.0f / fmaxf(sqrtf(ss), 1e-8f);
#pragma unroll
        for (int kk = 0; kk < 8; ++kk) {
            U16x8 t;
#pragma unroll
            for (int j = 0; j < 8; ++j) t.us[j] = f2bf(bf2f(qt[kk].us[j]) * invl);
            qf[kk] = t.s8;
        }
    }

    __syncthreads();   // drains DMA(tile 0)

    f32x4 zero = {0.f, 0.f, 0.f, 0.f};
    f32x4 o[16];       // per-wave PARTIAL O (16 keys x my 16 rows): [c-tile 16c]
#pragma unroll
    for (int j = 0; j < 16; ++j) o[j] = zero;
    float dl = 0.f;

    // GEMM1 A-frag source: my 16 key-rows of sGmc
    const unsigned short* gAbase = &sGmc[(kh * 16 + l15) * 256];
    const int rxor = (kh * 16 + l15) & 31;
    // GEMM2 B-frag source: chunk-of-4 XOR swizzle (matches goffB granule swizzle)
    const int chunkXor = (kh * 4 + quad) ^ (l15 & 14);
    const unsigned short* gBbase = &sGcm[l15 * 64 + (chunkXor << 2)];

    for (int mt = 0; mt < 32; ++mt) {
        // GEMM1 (swapped): S^T[16 keys][16 rows], K=256
        f32x4 sa = zero;
#pragma unroll
        for (int kk = 0; kk < 8; ++kk) {
            short8 ag = *(const short8*)&gAbase[((kk * 4 + quad) ^ rxor) << 3];
            sa = __builtin_amdgcn_mfma_f32_16x16x32_bf16(ag, qf[kk], sa, 0, 0, 0);
        }
        // p = exp(cos/tau); lane holds (q-row = l15, key = quad*4+r) -> already
        // the 16x16x16 A-frag layout. Accumulate denominator partial.
        U16x4 pk;
#pragma unroll
        for (int r = 0; r < 4; ++r) {
            float p = exp2f(sa[r] * 3.6067376022224085f);
            dl += p;
            pk.us[r] = f2bf(p);
        }
        __syncthreads();                    // barrier A: sGmc readers done, dmaB drained
        if (mt < 31) dmaA((mt + 1) * 64);   // covered by GEMM2, drained at barrier B

        // GEMM2 key-split: O_partial[16 rows][256 c] += P[16][16 keys] * V[16][256]
#pragma unroll
        for (int ct = 0; ct < 16; ++ct) {
            short4v bb = *(const short4v*)&gBbase[ct * 1024];
            o[ct] = mfma16x16(pk.s4, bb, o[ct]);
        }
        __syncthreads();                    // barrier B: sGcm readers done, dmaA drained
        if (mt < 31) dmaB((mt + 1) * 64);   // covered by next GEMM1, drained at barrier A
    }

    // ---- denominators: quad-reduce, publish per key-quarter per row ----
    {
        float d = dl;
        d += __shfl_xor(d, 16);
        d += __shfl_xor(d, 32);
        if (quad == 0) sDen[kh][rh * 16 + l15] = d;
    }

    // ---- O reduction: 4 static rounds (one per rh) through 64 KB LDS dump ----
    // slot(kh', j, quad, l15) = kh'*1024 + j*64 + quad*16 + l15  (f32x4 units)
    // All indices static (rule #20). red4 covers sMem[0,65536); sDen at 65536.
    f32x4* red4 = (f32x4*)sMem;
    const int wslot = kh * 1024 + quad * 16 + l15;       // + j*64
    const int rslot = (4 * kh) * 64 + quad * 16 + l15;   // + jj*64 + kh'*1024
    f32x4 oacc[4];

#define RED_ROUND(RH)                                                          \
    __syncthreads();                                                           \
    if (rh == (RH)) {                                                          \
        _Pragma("unroll")                                                      \
        for (int j = 0; j < 16; ++j) red4[wslot + j * 64] = o[j];              \
    }                                                                          \
    __syncthreads();                                                           \
    if (rh == (RH)) {                                                          \
        _Pragma("unroll")                                                      \
        for (int jj = 0; jj < 4; ++jj) {                                       \
            const int base = rslot + jj * 64;                                  \
            oacc[jj] = red4[base] + red4[base + 1024] +                        \
                       red4[base + 2048] + red4[base + 3072];                  \
        }                                                                      \
    }

    RED_ROUND(0)
    RED_ROUND(1)
    RED_ROUND(2)
    RED_ROUND(3)
#undef RED_ROUND

    // ---- epilogue: wave (kh, rh) owns rows [16rh,16rh+16), c [64kh, 64kh+64) ----
    const float* lb = l + ((size_t)b * N_ + row0 + rh * 16) * C_;
    float* ob = out + ((size_t)b * N_ + row0 + rh * 16) * C_;
#pragma unroll
    for (int r = 0; r < 4; ++r) {
        const int row = quad * 4 + r;
        const int grow = rh * 16 + row;
        const float inv = 1.f / (sDen[0][grow] + sDen[1][grow] + sDen[2][grow] + sDen[3][grow]);
        const size_t rb = (size_t)row * C_;
#pragma unroll
        for (int jj = 0; jj < 4; ++jj) {
            const int c = kh * 64 + jj * 16 + l15;
            ob[rb + c] = lb[rb + c] + oacc[jj][r] * inv;
        }
    }
}

extern "C" void kernel_launch(void* const* d_in, const int* in_sizes, int n_in,
                              void* d_out, int out_size, void* d_ws, size_t ws_size,
                              hipStream_t stream) {
    (void)in_sizes; (void)n_in; (void)out_size; (void)ws_size;
    const float* l = (const float*)d_in[0];
    const float* g = (const float*)d_in[1];
    float* outp = (float*)d_out;

    char* ws = (char*)d_ws;
    unsigned short* gmc = (unsigned short*)ws;                                   // 4 MB (normalized, [b][m][c])
    unsigned short* gcm = (unsigned short*)(ws + (size_t)B_ * M_ * C_ * 2);      // 4 MB (raw, [b][c][m])

    k_prep<<<dim3(M_ / 64, B_), 1024, 0, stream>>>(g, gcm, gmc);
    k_main<<<dim3(N_ / 64 * B_), 1024, 0, stream>>>(l, gcm, gmc, outp);
}